// Round 1
// 177.680 us; speedup vs baseline: 1.0076x; 1.0076x over previous
//
#include <hip/hip_runtime.h>
#include <hip/hip_bf16.h>
#include <math.h>

static constexpr int kC = 32, kR = 255, kE = 256;

// Static device scratch (graph-capture-safe). No atomics (round-5 lesson).
__device__ float g_q0kv[768];            // only [512..767] (= W_v·cls + b_v) used now
__device__ float g_qw[4 * 256];          // (q0_h^T W_k,h)*scale  [h][e]
__device__ float g_s0[4];                // score of key position 0 per head
__device__ float g_qb[4];                // (q0_h · b_k,h)*scale
__device__ float g_m[256 * 4 * 4];       // chunk max   [bc][chunk][h]
__device__ float g_l[256 * 4 * 4];       // chunk sum   [bc][chunk][h]
__device__ float g_part[256 * 4 * 4 * 256]; // partial xbar [bc][chunk][h][e]
// bf16 weight caches, e8-major transposed: index ((e>>3)*OUT + o)*8 + (e&7).
// Consumers load uint4 at (e8*OUT+t)*16B -> lane-consecutive (round-6 lesson).
__device__ unsigned short g_wv_bf[256 * 256];    // OUT=256, IN=256
__device__ unsigned short g_wout_bf[256 * 256];  // OUT=256, IN=256
__device__ unsigned short g_w1_bf[1024 * 256];   // OUT=1024, IN=256
__device__ unsigned short g_w2_bf[256 * 1024];   // OUT=256, IN=1024

__device__ inline unsigned short f2bf(float f) {
  __hip_bfloat16 h = __float2bfloat16(f);
  return __builtin_bit_cast(unsigned short, h);
}
__device__ inline float bflo(unsigned int u) { return __uint_as_float(u << 16); }
__device__ inline float bfhi(unsigned int u) { return __uint_as_float(u & 0xffff0000u); }

// ---- Fused setup (was k_setup_rows + k_setup_head):
//   blocks 0..3    : per-head qw/s0/qb; q0/kc rows recomputed in-block (removes
//                    the cross-kernel dependency on a separate row pass)
//   blocks 4..43   : LDS-tiled transposing bf16 casts (round-7/8 lessons)
//   blocks 44..107 : v rows of W_qkv·cls + b (wave-per-row, single 1KB load) ----
__global__ __launch_bounds__(256) void k_setup(const float* __restrict__ cls,
                                               const float* __restrict__ w_qkv,
                                               const float* __restrict__ b_qkv,
                                               const float* __restrict__ w_out,
                                               const float* __restrict__ w1,
                                               const float* __restrict__ w2) {
  const int t = threadIdx.x, wvi = t >> 6, l = t & 63;

  if (blockIdx.x >= 44) {  // ---- v rows 512..767: wave-per-row dot ----
    const int row = 512 + (blockIdx.x - 44) * 4 + wvi;
    float4 w4 = *((const float4*)(w_qkv + (size_t)row * 256) + l);
    float4 c4 = *((const float4*)cls + l);
    float a = w4.x * c4.x + w4.y * c4.y + w4.z * c4.z + w4.w * c4.w;
#pragma unroll
    for (int m = 1; m < 64; m <<= 1) a += __shfl_xor(a, m);
    if (l == 0) g_q0kv[row] = a + b_qkv[row];
    return;
  }

  if (blockIdx.x >= 4) {  // ---- cast tiles: 64 out-rows x 256 in-cols ----
    const int u = blockIdx.x - 4;  // 0..39
    const float* src;
    unsigned short* dst;
    int R, C, o0, e0;
    if (u < 4) { src = w_qkv + 512 * 256; dst = g_wv_bf; R = 256; C = 256; o0 = u * 64; e0 = 0; }
    else if (u < 8) { src = w_out; dst = g_wout_bf; R = 256; C = 256; o0 = (u - 4) * 64; e0 = 0; }
    else if (u < 24) { src = w1; dst = g_w1_bf; R = 1024; C = 256; o0 = (u - 8) * 64; e0 = 0; }
    else { const int v = u - 24; src = w2; dst = g_w2_bf; R = 256; C = 1024; o0 = (v >> 2) * 64; e0 = (v & 3) * 256; }

    __shared__ unsigned short tile[64 * 260];  // 520B row stride: 8B-aligned, 2-way banks (free)
    for (int r = wvi; r < 64; r += 4) {
      float4 v = *((const float4*)(src + (size_t)(o0 + r) * C + e0) + l);
      ushort4 ov;
      ov.x = f2bf(v.x); ov.y = f2bf(v.y); ov.z = f2bf(v.z); ov.w = f2bf(v.w);
      *(ushort4*)&tile[r * 260 + 4 * l] = ov;
    }
    __syncthreads();
    const int e80 = e0 >> 3;
    for (int e8l = wvi; e8l < 32; e8l += 4) {
      const unsigned int* tp = (const unsigned int*)&tile[l * 260 + e8l * 8];
      uint4 o;
      o.x = tp[0]; o.y = tp[1]; o.z = tp[2]; o.w = tp[3];
      *(uint4*)(dst + ((size_t)(e80 + e8l) * R + o0 + l) * 8) = o;
    }
    return;
  }

  // ---- head block h: recompute q0/kc rows in-block, then qw/s0/qb ----
  const int h = blockIdx.x;
  __shared__ float q0h[64];
  __shared__ float kch[64];
  {
    // 128 row-dots (64 q rows, 64 k rows); thread t: row r=t>>1, half=t&1
    const int r = t >> 1, half = t & 1;
    const int row = (r < 64) ? (h * 64 + r) : (256 + h * 64 + (r - 64));
    const float4* wp = (const float4*)(w_qkv + (size_t)row * 256 + half * 128);
    const float4* cp = (const float4*)cls + half * 32;
    float a = 0.f;
#pragma unroll 8
    for (int j = 0; j < 32; ++j) {
      float4 w4 = wp[j];
      float4 cv = cp[j];
      a += w4.x * cv.x + w4.y * cv.y + w4.z * cv.z + w4.w * cv.w;
    }
    a += __shfl_xor(a, 1);
    if (half == 0) {
      const float val = a + b_qkv[row];
      if (r < 64) q0h[r] = val; else kch[r - 64] = val;
    }
  }
  __syncthreads();

  float acc = 0.f;
#pragma unroll 8
  for (int j = 0; j < 64; ++j)
    acc += q0h[j] * w_qkv[(size_t)(256 + h * 64 + j) * 256 + t];
  g_qw[h * 256 + t] = acc * 0.125f;
  if (wvi == 0) {
    const float q = q0h[l];
    float pk = q * kch[l];                    // kc includes b_k
    float pb = q * b_qkv[256 + h * 64 + l];
#pragma unroll
    for (int m = 1; m < 64; m <<= 1) {
      pk += __shfl_xor(pk, m);
      pb += __shfl_xor(pb, m);
    }
    if (l == 0) {
      g_s0[h] = pk * 0.125f;
      g_qb[h] = pb * 0.125f;
    }
  }
}

// ---- Attention chunks: scores + chunk softmax + partial weighted sums ----
__global__ __launch_bounds__(256) void k_attn(const float* __restrict__ x,
                                              const int* __restrict__ real_cols,
                                              const int* __restrict__ real_rows) {
  const int bc = blockIdx.x, chunk = blockIdx.y;
  const int b = bc >> 5, c = bc & 31;
  if (c >= real_cols[b]) return;
  const int rr = real_rows[b];
  const int r0 = chunk * 64;
  const int nr = min(64, rr - r0);
  if (nr <= 0) return;

  __shared__ float xs[64][260];  // 1040B row stride: uniform bank windows
  __shared__ float qws[4][256];
  __shared__ float ps[4][64];
  const int t = threadIdx.x, wv = t >> 6, l = t & 63;

#pragma unroll
  for (int i = 0; i < 4; ++i) qws[i][t] = g_qw[i * 256 + t];

  const float* xb = x + ((size_t)bc * kR + r0) * kE;
  for (int r = wv; r < nr; r += 4)
    *(float4*)&xs[r][4 * l] = *(const float4*)(xb + (size_t)r * kE + 4 * l);
  __syncthreads();

  const int h = wv, row = l;
  float acc = 0.f;
  const float4* qrow = (const float4*)&qws[h][0];
  const float4* xrow = (const float4*)&xs[row][0];
#pragma unroll 8
  for (int e4 = 0; e4 < 64; ++e4) {
    float4 q4 = qrow[e4];
    float4 x4 = xrow[e4];
    acc += q4.x * x4.x + q4.y * x4.y + q4.z * x4.z + q4.w * x4.w;
  }
  float s = (row < nr) ? acc + g_qb[h] : -1e30f;
  float mx = s;
#pragma unroll
  for (int m = 1; m < 64; m <<= 1) mx = fmaxf(mx, __shfl_xor(mx, m));
  float p = (row < nr) ? __expf(s - mx) : 0.f;
  float lsum = p;
#pragma unroll
  for (int m = 1; m < 64; m <<= 1) lsum += __shfl_xor(lsum, m);
  ps[h][row] = p;
  if (l == 0) {
    g_m[(bc * 4 + chunk) * 4 + h] = mx;
    g_l[(bc * 4 + chunk) * 4 + h] = lsum;
  }
  __syncthreads();

  float a0 = 0.f, a1 = 0.f, a2 = 0.f, a3 = 0.f;
  for (int r2 = 0; r2 < nr; ++r2) {
    float xv = xs[r2][t];
    a0 += ps[0][r2] * xv;
    a1 += ps[1][r2] * xv;
    a2 += ps[2][r2] * xv;
    a3 += ps[3][r2] * xv;
  }
  float* pp = g_part + (size_t)(bc * 4 + chunk) * 4 * 256;
  pp[0 * 256 + t] = a0;
  pp[1 * 256 + t] = a1;
  pp[2 * 256 + t] = a2;
  pp[3 * 256 + t] = a3;
}

// ---- Fused per-token tail (was k_tail + k_ffn1 + k_ffn2):
//   merge -> xbar -> ctx -> mha -> LN (LDS) -> FFN1 (hidden in LDS) ->
//   FFN2 + residual + mask -> out. One block per (b,c) token; no g_ln/g_hact
//   global round-trips, two fewer launch/drain cycles. ----
__global__ __launch_bounds__(256) void k_token(const int* __restrict__ real_cols,
                                               const int* __restrict__ real_rows,
                                               const float* __restrict__ b_qkv,
                                               const float* __restrict__ b_out,
                                               const float* __restrict__ ln_g,
                                               const float* __restrict__ ln_b,
                                               const float* __restrict__ b1,
                                               const float* __restrict__ b2,
                                               float* __restrict__ out) {
  const int bc = blockIdx.x, b = bc >> 5, c = bc & 31;
  const int t = threadIdx.x, wv = t >> 6, l = t & 63;
  if (c >= real_cols[b]) {  // masked column: write the zero mask and leave
    out[(size_t)bc * 256 + t] = 0.f;
    return;
  }
  const int rr = real_rows[b];
  const int nch = (rr + 63) >> 6;

  __shared__ float xb[4][256];
  __shared__ float ctxs[256];
  __shared__ float lns[256];
  __shared__ float hs[1024];
  __shared__ float al[4][4];
  __shared__ float p0s[4];
  __shared__ float rb[2][4];

  if (t < 4) {  // flash-merge chunk stats, head h = t
    const int h = t;
    const float s0 = g_s0[h];
    float M = s0;
    for (int ch = 0; ch < nch; ++ch) M = fmaxf(M, g_m[(bc * 4 + ch) * 4 + h]);
    float lt = __expf(s0 - M);
    const float w0 = lt;
    float av[4] = {0.f, 0.f, 0.f, 0.f};
    for (int ch = 0; ch < nch; ++ch) {
      float e = __expf(g_m[(bc * 4 + ch) * 4 + h] - M);
      av[ch] = e;
      lt += g_l[(bc * 4 + ch) * 4 + h] * e;
    }
    const float inv = 1.f / lt;
#pragma unroll
    for (int ch = 0; ch < 4; ++ch) al[h][ch] = av[ch] * inv;
    p0s[h] = w0 * inv;
  }
  __syncthreads();

#pragma unroll
  for (int h = 0; h < 4; ++h) {
    float a = 0.f;
    for (int ch = 0; ch < nch; ++ch)
      a += al[h][ch] * g_part[(size_t)(bc * 4 + ch) * 4 * 256 + h * 256 + t];
    xb[h][t] = a;
  }
  __syncthreads();

  {  // ctx[f=t]; wave wv == head f>>6; e8-major W_v: load (e8*256+t) coalesced
    const int h = wv;
    const float p0 = p0s[h];
    float acc = p0 * g_q0kv[512 + t] + (1.f - p0) * b_qkv[512 + t];
    const uint4* wr = (const uint4*)g_wv_bf;
    const float4* v4p = (const float4*)&xb[h][0];
#pragma unroll 4
    for (int e8 = 0; e8 < 32; ++e8) {
      uint4 w = wr[e8 * 256 + t];
      float4 a = v4p[2 * e8], bb = v4p[2 * e8 + 1];
      acc += bflo(w.x) * a.x + bfhi(w.x) * a.y + bflo(w.y) * a.z + bfhi(w.y) * a.w +
             bflo(w.z) * bb.x + bfhi(w.z) * bb.y + bflo(w.w) * bb.z + bfhi(w.w) * bb.w;
    }
    ctxs[t] = acc;
  }
  __syncthreads();

  float mh;
  {  // mha[g=t]; e8-major W_out
    float acc = b_out[t];
    const uint4* wr = (const uint4*)g_wout_bf;
    const float4* c4 = (const float4*)&ctxs[0];
#pragma unroll 4
    for (int e8 = 0; e8 < 32; ++e8) {
      uint4 w = wr[e8 * 256 + t];
      float4 a = c4[2 * e8], bb = c4[2 * e8 + 1];
      acc += bflo(w.x) * a.x + bfhi(w.x) * a.y + bflo(w.y) * a.z + bfhi(w.y) * a.w +
             bflo(w.z) * bb.x + bfhi(w.z) * bb.y + bflo(w.w) * bb.z + bfhi(w.w) * bb.w;
    }
    mh = acc;
  }

  float s1 = mh, s2 = mh * mh;
#pragma unroll
  for (int m = 1; m < 64; m <<= 1) {
    s1 += __shfl_xor(s1, m);
    s2 += __shfl_xor(s2, m);
  }
  if (l == 0) {
    rb[0][wv] = s1;
    rb[1][wv] = s2;
  }
  __syncthreads();
  const float mu = (rb[0][0] + rb[0][1] + rb[0][2] + rb[0][3]) * (1.f / 256.f);
  const float msq = (rb[1][0] + rb[1][1] + rb[1][2] + rb[1][3]) * (1.f / 256.f);
  const float var = msq - mu * mu;
  const float lnv = (mh - mu) * rsqrtf(var + 1e-5f) * ln_g[t] + ln_b[t];
  lns[t] = lnv;
  __syncthreads();

  {  // FFN1: thread t computes f = t + 256k, k=0..3; e8-major W1, lns broadcast
    const uint4* wr = (const uint4*)g_w1_bf;
    float acc1[4];
#pragma unroll
    for (int k = 0; k < 4; ++k) acc1[k] = b1[t + 256 * k];
    for (int e8 = 0; e8 < 32; ++e8) {
      const float4 a = *(const float4*)&lns[8 * e8];
      const float4 bbv = *(const float4*)&lns[8 * e8 + 4];
#pragma unroll
      for (int k = 0; k < 4; ++k) {
        uint4 w = wr[e8 * 1024 + t + 256 * k];
        acc1[k] += bflo(w.x) * a.x + bfhi(w.x) * a.y + bflo(w.y) * a.z + bfhi(w.y) * a.w +
                   bflo(w.z) * bbv.x + bfhi(w.z) * bbv.y + bflo(w.w) * bbv.z + bfhi(w.w) * bbv.w;
      }
    }
#pragma unroll
    for (int k = 0; k < 4; ++k) hs[t + 256 * k] = fmaxf(acc1[k], 0.f);
  }
  __syncthreads();

  {  // FFN2 + residual; thread t computes e = t; e8-major W2, hs broadcast
    const uint4* wr = (const uint4*)g_w2_bf;
    const float4* h4 = (const float4*)&hs[0];
    float acc = b2[t];
    for (int f8 = 0; f8 < 128; ++f8) {
      uint4 w = wr[f8 * 256 + t];
      float4 a = h4[2 * f8], bb = h4[2 * f8 + 1];
      acc += bflo(w.x) * a.x + bfhi(w.x) * a.y + bflo(w.y) * a.z + bfhi(w.y) * a.w +
             bflo(w.z) * bb.x + bfhi(w.z) * bb.y + bflo(w.w) * bb.z + bfhi(w.w) * bb.w;
    }
    out[(size_t)bc * 256 + t] = lnv + acc;
  }
}

extern "C" void kernel_launch(void* const* d_in, const int* in_sizes, int n_in,
                              void* d_out, int out_size, void* d_ws, size_t ws_size,
                              hipStream_t stream) {
  const float* x = (const float*)d_in[0];
  const int* real_cols = (const int*)d_in[1];
  const int* real_rows = (const int*)d_in[2];
  const float* cls = (const float*)d_in[3];
  const float* w_qkv = (const float*)d_in[4];
  const float* b_qkv = (const float*)d_in[5];
  const float* w_out = (const float*)d_in[6];
  const float* b_out = (const float*)d_in[7];
  const float* ln_g = (const float*)d_in[8];
  const float* ln_b = (const float*)d_in[9];
  const float* w1 = (const float*)d_in[10];
  const float* b1 = (const float*)d_in[11];
  const float* w2 = (const float*)d_in[12];
  const float* b2 = (const float*)d_in[13];
  float* out = (float*)d_out;
  (void)in_sizes; (void)n_in; (void)out_size; (void)d_ws; (void)ws_size;

  k_setup<<<108, 256, 0, stream>>>(cls, w_qkv, b_qkv, w_out, w1, w2);
  k_attn<<<dim3(256, 4), 256, 0, stream>>>(x, real_cols, real_rows);
  k_token<<<256, 256, 0, stream>>>(real_cols, real_rows, b_qkv, b_out, ln_g, ln_b, b1, b2, out);
}

// Round 2
// 154.742 us; speedup vs baseline: 1.1569x; 1.1482x over previous
//
#include <hip/hip_runtime.h>
#include <hip/hip_bf16.h>
#include <math.h>

static constexpr int kC = 32, kR = 255, kE = 256;

// Static device scratch (graph-capture-safe). No atomics (round-5 lesson).
__device__ float g_q0kv[768];            // only [512..767] (= W_v·cls + b_v) used now
__device__ float g_qw[4 * 256];          // (q0_h^T W_k,h)*scale  [h][e]
__device__ float g_s0[4];                // score of key position 0 per head
__device__ float g_qb[4];                // (q0_h · b_k,h)*scale
__device__ float g_m[256 * 4 * 4];       // chunk max   [bc][chunk][h]
__device__ float g_l[256 * 4 * 4];       // chunk sum   [bc][chunk][h]
__device__ float g_part[256 * 4 * 4 * 256]; // partial xbar [bc][chunk][h][e]
// bf16 weight caches, e8-major transposed: index ((e>>3)*OUT + o)*8 + (e&7).
// Consumers load uint4 at (e8*OUT+t)*16B -> lane-consecutive (round-6 lesson).
__device__ unsigned short g_wv_bf[256 * 256];    // OUT=256, IN=256
__device__ unsigned short g_wout_bf[256 * 256];  // OUT=256, IN=256
__device__ unsigned short g_w1_bf[1024 * 256];   // OUT=1024, IN=256
__device__ unsigned short g_w2_bf[256 * 1024];   // OUT=256, IN=1024

__device__ inline unsigned short f2bf(float f) {
  __hip_bfloat16 h = __float2bfloat16(f);
  return __builtin_bit_cast(unsigned short, h);
}
__device__ inline float bflo(unsigned int u) { return __uint_as_float(u << 16); }
__device__ inline float bfhi(unsigned int u) { return __uint_as_float(u & 0xffff0000u); }

// ---- Head setup: 4 blocks, one per head. q0/kc rows recomputed in-block,
//      then qw/s0/qb. Tiny serialized stage; everything else rides elsewhere. ----
__global__ __launch_bounds__(256) void k_heads(const float* __restrict__ cls,
                                               const float* __restrict__ w_qkv,
                                               const float* __restrict__ b_qkv) {
  const int t = threadIdx.x, wvi = t >> 6, l = t & 63;
  const int h = blockIdx.x;
  __shared__ float q0h[64];
  __shared__ float kch[64];
  {
    // 128 row-dots (64 q rows, 64 k rows); thread t: row r=t>>1, half=t&1
    const int r = t >> 1, half = t & 1;
    const int row = (r < 64) ? (h * 64 + r) : (256 + h * 64 + (r - 64));
    const float4* wp = (const float4*)(w_qkv + (size_t)row * 256 + half * 128);
    const float4* cp = (const float4*)cls + half * 32;
    float a = 0.f;
#pragma unroll 8
    for (int j = 0; j < 32; ++j) {
      float4 w4 = wp[j];
      float4 cv = cp[j];
      a += w4.x * cv.x + w4.y * cv.y + w4.z * cv.z + w4.w * cv.w;
    }
    a += __shfl_xor(a, 1);
    if (half == 0) {
      const float val = a + b_qkv[row];
      if (r < 64) q0h[r] = val; else kch[r - 64] = val;
    }
  }
  __syncthreads();

  float acc = 0.f;
#pragma unroll 8
  for (int j = 0; j < 64; ++j)
    acc += q0h[j] * w_qkv[(size_t)(256 + h * 64 + j) * 256 + t];
  g_qw[h * 256 + t] = acc * 0.125f;
  if (wvi == 0) {
    const float q = q0h[l];
    float pk = q * kch[l];                    // kc includes b_k
    float pb = q * b_qkv[256 + h * 64 + l];
#pragma unroll
    for (int m = 1; m < 64; m <<= 1) {
      pk += __shfl_xor(pk, m);
      pb += __shfl_xor(pb, m);
    }
    if (l == 0) {
      g_s0[h] = pk * 0.125f;
      g_qb[h] = pb * 0.125f;
    }
  }
}

// ---- Attention chunks + rider blocks.
//   blocks 0..1023    : scores + chunk softmax + partial weighted sums
//   blocks 1024..1063 : LDS-tiled transposing bf16 casts (feed k_token only)
//   blocks 1064..1127 : v rows of W_qkv·cls + b (wave-per-row 1KB dot)
//   Shared memory is one carved buffer so the cast tile does not inflate the
//   attention path's LDS footprint (occupancy stays 2 blocks/CU). ----
__global__ __launch_bounds__(256) void k_attn(const float* __restrict__ x,
                                              const int* __restrict__ real_cols,
                                              const int* __restrict__ real_rows,
                                              const float* __restrict__ cls,
                                              const float* __restrict__ w_qkv,
                                              const float* __restrict__ b_qkv,
                                              const float* __restrict__ w_out,
                                              const float* __restrict__ w1,
                                              const float* __restrict__ w2) {
  const int t = threadIdx.x, wv = t >> 6, l = t & 63;
  const int bid = blockIdx.x;
  __shared__ __align__(16) char smem[71680];

  if (bid >= 1064) {  // ---- v rows 512..767: wave-per-row dot ----
    const int row = 512 + (bid - 1064) * 4 + wv;
    float4 w4 = *((const float4*)(w_qkv + (size_t)row * 256) + l);
    float4 c4 = *((const float4*)cls + l);
    float a = w4.x * c4.x + w4.y * c4.y + w4.z * c4.z + w4.w * c4.w;
#pragma unroll
    for (int m = 1; m < 64; m <<= 1) a += __shfl_xor(a, m);
    if (l == 0) g_q0kv[row] = a + b_qkv[row];
    return;
  }

  if (bid >= 1024) {  // ---- cast tiles: 64 out-rows x 256 in-cols ----
    const int u = bid - 1024;  // 0..39
    const float* src;
    unsigned short* dst;
    int R, C, o0, e0;
    if (u < 4) { src = w_qkv + 512 * 256; dst = g_wv_bf; R = 256; C = 256; o0 = u * 64; e0 = 0; }
    else if (u < 8) { src = w_out; dst = g_wout_bf; R = 256; C = 256; o0 = (u - 4) * 64; e0 = 0; }
    else if (u < 24) { src = w1; dst = g_w1_bf; R = 1024; C = 256; o0 = (u - 8) * 64; e0 = 0; }
    else { const int v = u - 24; src = w2; dst = g_w2_bf; R = 256; C = 1024; o0 = (v >> 2) * 64; e0 = (v & 3) * 256; }

    unsigned short* tile = (unsigned short*)smem;  // 64*260 ushort = 33280 B
    for (int r = wv; r < 64; r += 4) {
      float4 v = *((const float4*)(src + (size_t)(o0 + r) * C + e0) + l);
      ushort4 ov;
      ov.x = f2bf(v.x); ov.y = f2bf(v.y); ov.z = f2bf(v.z); ov.w = f2bf(v.w);
      *(ushort4*)&tile[r * 260 + 4 * l] = ov;
    }
    __syncthreads();
    const int e80 = e0 >> 3;
    for (int e8l = wv; e8l < 32; e8l += 4) {
      const unsigned int* tp = (const unsigned int*)&tile[l * 260 + e8l * 8];
      uint4 o;
      o.x = tp[0]; o.y = tp[1]; o.z = tp[2]; o.w = tp[3];
      *(uint4*)(dst + ((size_t)(e80 + e8l) * R + o0 + l) * 8) = o;
    }
    return;
  }

  // ---- attention chunk blocks (code unchanged from proven version) ----
  const int bc = bid >> 2, chunk = bid & 3;
  const int b = bc >> 5, c = bc & 31;
  if (c >= real_cols[b]) return;
  const int rr = real_rows[b];
  const int r0 = chunk * 64;
  const int nr = min(64, rr - r0);
  if (nr <= 0) return;

  float (*xs)[260] = (float(*)[260])smem;                    // 66560 B
  float (*qws)[256] = (float(*)[256])(smem + 66560);         //  4096 B
  float (*ps)[64] = (float(*)[64])(smem + 70656);            //  1024 B

#pragma unroll
  for (int i = 0; i < 4; ++i) qws[i][t] = g_qw[i * 256 + t];

  const float* xb = x + ((size_t)bc * kR + r0) * kE;
  for (int r = wv; r < nr; r += 4)
    *(float4*)&xs[r][4 * l] = *(const float4*)(xb + (size_t)r * kE + 4 * l);
  __syncthreads();

  const int h = wv, row = l;
  float acc = 0.f;
  const float4* qrow = (const float4*)&qws[h][0];
  const float4* xrow = (const float4*)&xs[row][0];
#pragma unroll 8
  for (int e4 = 0; e4 < 64; ++e4) {
    float4 q4 = qrow[e4];
    float4 x4 = xrow[e4];
    acc += q4.x * x4.x + q4.y * x4.y + q4.z * x4.z + q4.w * x4.w;
  }
  float s = (row < nr) ? acc + g_qb[h] : -1e30f;
  float mx = s;
#pragma unroll
  for (int m = 1; m < 64; m <<= 1) mx = fmaxf(mx, __shfl_xor(mx, m));
  float p = (row < nr) ? __expf(s - mx) : 0.f;
  float lsum = p;
#pragma unroll
  for (int m = 1; m < 64; m <<= 1) lsum += __shfl_xor(lsum, m);
  ps[h][row] = p;
  if (l == 0) {
    g_m[(bc * 4 + chunk) * 4 + h] = mx;
    g_l[(bc * 4 + chunk) * 4 + h] = lsum;
  }
  __syncthreads();

  float a0 = 0.f, a1 = 0.f, a2 = 0.f, a3 = 0.f;
  for (int r2 = 0; r2 < nr; ++r2) {
    float xv = xs[r2][t];
    a0 += ps[0][r2] * xv;
    a1 += ps[1][r2] * xv;
    a2 += ps[2][r2] * xv;
    a3 += ps[3][r2] * xv;
  }
  float* pp = g_part + (size_t)(bc * 4 + chunk) * 4 * 256;
  pp[0 * 256 + t] = a0;
  pp[1 * 256 + t] = a1;
  pp[2 * 256 + t] = a2;
  pp[3 * 256 + t] = a3;
}

// ---- Fused per-token tail, WIDE: 1024 threads (16 waves/CU) to hide L2
//      latency (round-1 lesson: 4 waves -> VALUBusy 14%, latency-bound).
//      ctx/mha/FFN2 are split-K-4 across thread groups; FFN1 is one f per
//      thread. Same loads, 4x memory-level parallelism. ----
__global__ __launch_bounds__(1024) void k_token(const int* __restrict__ real_cols,
                                                const int* __restrict__ real_rows,
                                                const float* __restrict__ b_qkv,
                                                const float* __restrict__ b_out,
                                                const float* __restrict__ ln_g,
                                                const float* __restrict__ ln_b,
                                                const float* __restrict__ b1,
                                                const float* __restrict__ b2,
                                                float* __restrict__ out) {
  const int bc = blockIdx.x, b = bc >> 5, c = bc & 31;
  const int t = threadIdx.x, wv = t >> 6, l = t & 63;
  if (c >= real_cols[b]) {  // masked column: write the zero mask and leave
    if (t < 256) out[(size_t)bc * 256 + t] = 0.f;
    return;
  }
  const int rr = real_rows[b];
  const int nch = (rr + 63) >> 6;

  __shared__ float xb[4][256];
  __shared__ float part[4][256];  // split-K partials (reused per phase)
  __shared__ float ctxs[256];
  __shared__ float lns[256];
  __shared__ float hs[1024];
  __shared__ float al[4][4];
  __shared__ float p0s[4];
  __shared__ float rb[2][4];

  if (t < 4) {  // flash-merge chunk stats, head h = t
    const int h = t;
    const float s0 = g_s0[h];
    float M = s0;
    for (int ch = 0; ch < nch; ++ch) M = fmaxf(M, g_m[(bc * 4 + ch) * 4 + h]);
    float lt = __expf(s0 - M);
    const float w0 = lt;
    float av[4] = {0.f, 0.f, 0.f, 0.f};
    for (int ch = 0; ch < nch; ++ch) {
      float e = __expf(g_m[(bc * 4 + ch) * 4 + h] - M);
      av[ch] = e;
      lt += g_l[(bc * 4 + ch) * 4 + h] * e;
    }
    const float inv = 1.f / lt;
#pragma unroll
    for (int ch = 0; ch < 4; ++ch) al[h][ch] = av[ch] * inv;
    p0s[h] = w0 * inv;
  }
  __syncthreads();

  {  // xbar merge: thread t -> (h = t>>8, e = t&255)
    const int h = t >> 8, e = t & 255;
    float a = 0.f;
    for (int ch = 0; ch < nch; ++ch)
      a += al[h][ch] * g_part[(size_t)(bc * 4 + ch) * 4 * 256 + h * 256 + e];
    xb[h][e] = a;
  }
  __syncthreads();

  {  // ctx: f = t&255, split-K group q = t>>8 handles e8 in [8q, 8q+8)
    const int f = t & 255, q = t >> 8, h = f >> 6;
    const uint4* wr = (const uint4*)g_wv_bf;
    const float4* v4p = (const float4*)&xb[h][0];
    float acc = 0.f;
#pragma unroll
    for (int i = 0; i < 8; ++i) {
      const int e8 = q * 8 + i;
      uint4 w = wr[e8 * 256 + f];
      float4 a = v4p[2 * e8], bb = v4p[2 * e8 + 1];
      acc += bflo(w.x) * a.x + bfhi(w.x) * a.y + bflo(w.y) * a.z + bfhi(w.y) * a.w +
             bflo(w.z) * bb.x + bfhi(w.z) * bb.y + bflo(w.w) * bb.z + bfhi(w.w) * bb.w;
    }
    part[q][f] = acc;
  }
  __syncthreads();
  if (t < 256) {
    const int h = t >> 6;
    const float p0 = p0s[h];
    ctxs[t] = part[0][t] + part[1][t] + part[2][t] + part[3][t] +
              p0 * g_q0kv[512 + t] + (1.f - p0) * b_qkv[512 + t];
  }
  __syncthreads();

  {  // mha: g = t&255, split-K-4 over e8; e8-major W_out
    const int g = t & 255, q = t >> 8;
    const uint4* wr = (const uint4*)g_wout_bf;
    const float4* c4 = (const float4*)&ctxs[0];
    float acc = 0.f;
#pragma unroll
    for (int i = 0; i < 8; ++i) {
      const int e8 = q * 8 + i;
      uint4 w = wr[e8 * 256 + g];
      float4 a = c4[2 * e8], bb = c4[2 * e8 + 1];
      acc += bflo(w.x) * a.x + bfhi(w.x) * a.y + bflo(w.y) * a.z + bfhi(w.y) * a.w +
             bflo(w.z) * bb.x + bfhi(w.z) * bb.y + bflo(w.w) * bb.z + bfhi(w.w) * bb.w;
    }
    part[q][g] = acc;
  }
  __syncthreads();
  float mh = 0.f;
  if (t < 256) {
    mh = part[0][t] + part[1][t] + part[2][t] + part[3][t] + b_out[t];
    float s1 = mh, s2 = mh * mh;
#pragma unroll
    for (int m = 1; m < 64; m <<= 1) {
      s1 += __shfl_xor(s1, m);
      s2 += __shfl_xor(s2, m);
    }
    if (l == 0) {
      rb[0][wv] = s1;
      rb[1][wv] = s2;
    }
  }
  __syncthreads();
  if (t < 256) {
    const float mu = (rb[0][0] + rb[0][1] + rb[0][2] + rb[0][3]) * (1.f / 256.f);
    const float msq = (rb[1][0] + rb[1][1] + rb[1][2] + rb[1][3]) * (1.f / 256.f);
    const float var = msq - mu * mu;
    lns[t] = (mh - mu) * rsqrtf(var + 1e-5f) * ln_g[t] + ln_b[t];
  }
  __syncthreads();

  {  // FFN1: thread t computes f = t; e8-major W1, lns broadcast from LDS
    const uint4* wr = (const uint4*)g_w1_bf;
    float acc = b1[t];
#pragma unroll
    for (int e8 = 0; e8 < 32; ++e8) {
      uint4 w = wr[e8 * 1024 + t];
      const float4 a = *(const float4*)&lns[8 * e8];
      const float4 bbv = *(const float4*)&lns[8 * e8 + 4];
      acc += bflo(w.x) * a.x + bfhi(w.x) * a.y + bflo(w.y) * a.z + bfhi(w.y) * a.w +
             bflo(w.z) * bbv.x + bfhi(w.z) * bbv.y + bflo(w.w) * bbv.z + bfhi(w.w) * bbv.w;
    }
    hs[t] = fmaxf(acc, 0.f);
  }
  __syncthreads();

  {  // FFN2: e = t&255, split-K group q = t>>8 handles f8 in [32q, 32q+32)
    const int e = t & 255, q = t >> 8;
    const uint4* wr = (const uint4*)g_w2_bf;
    const float4* h4 = (const float4*)&hs[0];
    float acc = 0.f;
#pragma unroll 8
    for (int i = 0; i < 32; ++i) {
      const int f8 = q * 32 + i;
      uint4 w = wr[f8 * 256 + e];
      float4 a = h4[2 * f8], bb = h4[2 * f8 + 1];
      acc += bflo(w.x) * a.x + bfhi(w.x) * a.y + bflo(w.y) * a.z + bfhi(w.y) * a.w +
             bflo(w.z) * bb.x + bfhi(w.z) * bb.y + bflo(w.w) * bb.z + bfhi(w.w) * bb.w;
    }
    part[q][e] = acc;
  }
  __syncthreads();
  if (t < 256)
    out[(size_t)bc * 256 + t] =
        lns[t] + part[0][t] + part[1][t] + part[2][t] + part[3][t] + b2[t];
}

extern "C" void kernel_launch(void* const* d_in, const int* in_sizes, int n_in,
                              void* d_out, int out_size, void* d_ws, size_t ws_size,
                              hipStream_t stream) {
  const float* x = (const float*)d_in[0];
  const int* real_cols = (const int*)d_in[1];
  const int* real_rows = (const int*)d_in[2];
  const float* cls = (const float*)d_in[3];
  const float* w_qkv = (const float*)d_in[4];
  const float* b_qkv = (const float*)d_in[5];
  const float* w_out = (const float*)d_in[6];
  const float* b_out = (const float*)d_in[7];
  const float* ln_g = (const float*)d_in[8];
  const float* ln_b = (const float*)d_in[9];
  const float* w1 = (const float*)d_in[10];
  const float* b1 = (const float*)d_in[11];
  const float* w2 = (const float*)d_in[12];
  const float* b2 = (const float*)d_in[13];
  float* out = (float*)d_out;
  (void)in_sizes; (void)n_in; (void)out_size; (void)d_ws; (void)ws_size;

  k_heads<<<4, 256, 0, stream>>>(cls, w_qkv, b_qkv);
  k_attn<<<1128, 256, 0, stream>>>(x, real_cols, real_rows, cls, w_qkv, b_qkv, w_out, w1, w2);
  k_token<<<256, 1024, 0, stream>>>(real_cols, real_rows, b_qkv, b_out, ln_g, ln_b, b1, b2, out);
}